// Round 1
// baseline (1341.585 us; speedup 1.0000x reference)
//
#include <hip/hip_runtime.h>
#include <math.h>

#define NB 32
#define NL 512
#define ND 384
#define NH 6
#define NCP 52
#define NC 50

// XOR swizzle for [row][64] f32 LDS tiles: permutes 16B chunks, keeps 4-chunks contiguous.
__device__ __forceinline__ int swz(int row, int k) {
    return k ^ (((row >> 2) & 7) << 2);
}

// ---------------- zero accumulators ----------------
__global__ void zero_kernel(float4* zb) {
    int idx = blockIdx.x * 256 + threadIdx.x;
    float4 z; z.x = 0.f; z.y = 0.f; z.z = 0.f; z.w = 0.f;
    for (int i = idx; i < 25000; i += 64 * 256) zb[i] = z;
}

// ---------------- embedding + tfidf weight + q2 ----------------
__global__ __launch_bounds__(384) void embed_kernel(
    const int* __restrict__ tids, const int* __restrict__ TFs, const int* __restrict__ DFs,
    const float* __restrict__ emb, float* __restrict__ hw, float* __restrict__ q2) {
    int t = threadIdx.x;
    int bl = blockIdx.x;               // 0..B*L-1
    int b = bl >> 9, l = bl & 511;
    int tid = tids[bl];
    float tf = log1pf(fminf((float)TFs[bl], 20.f));
    float idf = 1.f / logf((float)DFs[bl] + 2.f);
    float wt = tf * idf;
    float hv = emb[(size_t)tid * ND + t] * wt;
    int hh = t >> 6, dd = t & 63;
    hw[((size_t)(b * NH + hh) * NL + l) * 64 + dd] = hv;
    float q = hv * hv;
    for (int off = 1; off < 64; off <<= 1) q += __shfl_xor(q, off);
    if (dd == 0) q2[(b * NH + hh) * NL + l] = q;
}

// ---------------- pairwise distance + BN stats (per head) ----------------
__global__ __launch_bounds__(256) void dist_kernel(
    const float* __restrict__ hw, const float* __restrict__ q2g,
    float* __restrict__ co, double* __restrict__ stats, int h) {
    __shared__ float hjs[512 * 64];
    __shared__ float his[64 * 64];
    __shared__ float q2j[512];
    __shared__ float q2i[64];
    __shared__ float red[8];
    int t = threadIdx.x;
    int b = blockIdx.x >> 3;
    int i0 = (blockIdx.x & 7) << 6;
    const float* hb = hw + (size_t)(b * NH + h) * (NL * 64);
    for (int it = 0; it < 32; ++it) {
        int f4i = t + (it << 8);
        int row = f4i >> 4;
        int kc = (f4i & 15) << 2;
        float4 v = *(const float4*)(hb + row * 64 + kc);
        *(float4*)(hjs + row * 64 + swz(row, kc)) = v;
    }
    for (int it = 0; it < 4; ++it) {
        int f4i = t + (it << 8);
        int row = f4i >> 4;
        int kc = (f4i & 15) << 2;
        float4 v = *(const float4*)(hb + (i0 + row) * 64 + kc);
        *(float4*)(his + row * 64 + swz(row, kc)) = v;
    }
    const float* q2b = q2g + (b * NH + h) * NL;
    q2j[t] = q2b[t];
    q2j[t + 256] = q2b[t + 256];
    if (t < 64) q2i[t] = q2b[i0 + t];
    __syncthreads();

    int tx = t & 15, ty = t >> 4;
    float lsum = 0.f, lss = 0.f;
    for (int jj = 0; jj < 8; ++jj) {
        int jb = (jj << 6) + (tx << 2);
        float acc[4][4] = {};
        for (int kc = 0; kc < 64; kc += 4) {
            float4 a[4], bb[4];
#pragma unroll
            for (int r = 0; r < 4; ++r)
                a[r] = *(const float4*)(his + (ty * 4 + r) * 64 + swz(ty * 4 + r, kc));
#pragma unroll
            for (int c = 0; c < 4; ++c)
                bb[c] = *(const float4*)(hjs + (jb + c) * 64 + swz(jb + c, kc));
#pragma unroll
            for (int r = 0; r < 4; ++r)
#pragma unroll
                for (int c = 0; c < 4; ++c)
                    acc[r][c] += a[r].x * bb[c].x + a[r].y * bb[c].y + a[r].z * bb[c].z + a[r].w * bb[c].w;
        }
#pragma unroll
        for (int r = 0; r < 4; ++r) {
            int i = ty * 4 + r;
            float4 o;
            float q2iv = q2i[i];
            float d0 = q2iv + q2j[jb + 0] - 2.f * acc[r][0];
            float d1 = q2iv + q2j[jb + 1] - 2.f * acc[r][1];
            float d2 = q2iv + q2j[jb + 2] - 2.f * acc[r][2];
            float d3 = q2iv + q2j[jb + 3] - 2.f * acc[r][3];
            o.x = sqrtf(fmaxf(d0, 0.f) + 1e-12f);
            o.y = sqrtf(fmaxf(d1, 0.f) + 1e-12f);
            o.z = sqrtf(fmaxf(d2, 0.f) + 1e-12f);
            o.w = sqrtf(fmaxf(d3, 0.f) + 1e-12f);
            lsum += o.x + o.y + o.z + o.w;
            lss += o.x * o.x + o.y * o.y + o.z * o.z + o.w * o.w;
            *(float4*)(co + ((size_t)b * NL + i0 + i) * NL + jb) = o;
        }
    }
    for (int off = 1; off < 64; off <<= 1) {
        lsum += __shfl_xor(lsum, off);
        lss += __shfl_xor(lss, off);
    }
    if ((t & 63) == 0) { red[(t >> 6) * 2] = lsum; red[(t >> 6) * 2 + 1] = lss; }
    __syncthreads();
    if (t == 0) {
        float s = 0.f, ss = 0.f;
        for (int w = 0; w < 4; ++w) { s += red[w * 2]; ss += red[w * 2 + 1]; }
        atomicAdd(&stats[h * 2], (double)s);
        atomicAdd(&stats[h * 2 + 1], (double)ss);
    }
}

// ---------------- finalize BN affine for head h ----------------
__global__ void fin_kernel(const double* __restrict__ stats, const float* __restrict__ gamma,
                           const float* __restrict__ beta, float* __restrict__ bnab, int h) {
    if (threadIdx.x == 0) {
        double n = (double)NB * NL * NL;
        double mu = stats[h * 2] / n;
        double var = stats[h * 2 + 1] / n - mu * mu;
        double inv = 1.0 / sqrt(var + 1e-5);
        double a = (double)gamma[h] * inv;
        bnab[0] = (float)a;
        bnab[1] = (float)((double)beta[h] - mu * a);
    }
}

// ---------------- per-row softmax stats (per head) ----------------
__global__ __launch_bounds__(256) void rowstats_kernel(
    const float* __restrict__ co, const int* __restrict__ tids, const float* __restrict__ bnab,
    float* __restrict__ rowm, float* __restrict__ rowsum) {
    int wv = threadIdx.x >> 6, lane = threadIdx.x & 63;
    int r = blockIdx.x * 4 + wv;       // global row 0..B*L-1
    int b = r >> 9, i = r & 511;
    float a = bnab[0], bb = bnab[1];
    bool padi = tids[(b << 9) + i] != 0;
    const float* row = co + (size_t)r * NL;
    float s[8];
#pragma unroll
    for (int u2 = 0; u2 < 2; ++u2) {
        int j0 = (u2 << 8) + (lane << 2);
        float4 v = *(const float4*)(row + j0);
        int4 tj = *(const int4*)(tids + (b << 9) + j0);
        s[u2 * 4 + 0] = (padi && tj.x != 0) ? a * v.x + bb : 0.f;
        s[u2 * 4 + 1] = (padi && tj.y != 0) ? a * v.y + bb : 0.f;
        s[u2 * 4 + 2] = (padi && tj.z != 0) ? a * v.z + bb : 0.f;
        s[u2 * 4 + 3] = (padi && tj.w != 0) ? a * v.w + bb : 0.f;
    }
    float m = s[0];
#pragma unroll
    for (int u = 1; u < 8; ++u) m = fmaxf(m, s[u]);
    for (int off = 1; off < 64; off <<= 1) m = fmaxf(m, __shfl_xor(m, off));
    float sum = 0.f;
#pragma unroll
    for (int u = 0; u < 8; ++u) sum += __expf(s[u] - m);
    for (int off = 1; off < 64; off <<= 1) sum += __shfl_xor(sum, off);
    if (lane == 0) { rowm[r] = m; rowsum[r] = sum; }
}

// ---------------- softmax + PV + column sums (per head) ----------------
__global__ __launch_bounds__(256) void pv_kernel(
    const float* __restrict__ co, const float* __restrict__ hw, const int* __restrict__ tids,
    const float* __restrict__ bnab, const float* __restrict__ rowm, const float* __restrict__ rowsum,
    float* __restrict__ Vcat, float* __restrict__ colsum, int h) {
    __shared__ float P[64 * 64];
    __shared__ float Vt[64 * 64];
    __shared__ float mi[64], isi[64];
    __shared__ int padi[64];
    __shared__ float csum[4][64];
    int t = threadIdx.x;
    int b = blockIdx.x >> 3;
    int i0 = (blockIdx.x & 7) << 6;
    float a = bnab[0], bb = bnab[1];
    if (t < 64) {
        int r = (b << 9) + i0 + t;
        mi[t] = rowm[r];
        isi[t] = 1.f / rowsum[r];
        padi[t] = tids[r] != 0;
    }
    __syncthreads();
    int tx = t & 15, ty = t >> 4;
    float acc[4][4] = {};
    for (int jt = 0; jt < 8; ++jt) {
        // stage P (softmax probabilities)
        {
            int sr = t >> 2, q = t & 3;
            bool pi = padi[sr] != 0;
            float mm = mi[sr], ii = isi[sr];
#pragma unroll
            for (int u = 0; u < 4; ++u) {
                int col = (q << 4) + (u << 2);
                int j = (jt << 6) + col;
                float4 v = *(const float4*)(co + ((size_t)(b << 9) + i0 + sr) * NL + j);
                int4 tj = *(const int4*)(tids + (b << 9) + j);
                float4 p;
                p.x = __expf(((pi && tj.x != 0) ? a * v.x + bb : 0.f) - mm) * ii;
                p.y = __expf(((pi && tj.y != 0) ? a * v.y + bb : 0.f) - mm) * ii;
                p.z = __expf(((pi && tj.z != 0) ? a * v.z + bb : 0.f) - mm) * ii;
                p.w = __expf(((pi && tj.w != 0) ? a * v.w + bb : 0.f) - mm) * ii;
                *(float4*)(P + sr * 64 + swz(sr, col)) = p;
            }
        }
        // stage V tile
        {
            const float* hb = hw + (size_t)(b * NH + h) * (NL * 64) + (size_t)(jt << 6) * 64;
#pragma unroll
            for (int it = 0; it < 4; ++it) {
                int f4i = t + (it << 8);
                int row = f4i >> 4, kc = (f4i & 15) << 2;
                float4 v = *(const float4*)(hb + row * 64 + kc);
                *(float4*)(Vt + row * 64 + swz(row, kc)) = v;
            }
        }
        __syncthreads();
        // PV accumulate
        for (int jc = 0; jc < 64; jc += 4) {
            float4 pa[4], vb[4];
#pragma unroll
            for (int r = 0; r < 4; ++r)
                pa[r] = *(const float4*)(P + (ty * 4 + r) * 64 + swz(ty * 4 + r, jc));
#pragma unroll
            for (int u = 0; u < 4; ++u)
                vb[u] = *(const float4*)(Vt + (jc + u) * 64 + swz(jc + u, tx << 2));
#pragma unroll
            for (int r = 0; r < 4; ++r) {
                acc[r][0] += pa[r].x * vb[0].x + pa[r].y * vb[1].x + pa[r].z * vb[2].x + pa[r].w * vb[3].x;
                acc[r][1] += pa[r].x * vb[0].y + pa[r].y * vb[1].y + pa[r].z * vb[2].y + pa[r].w * vb[3].y;
                acc[r][2] += pa[r].x * vb[0].z + pa[r].y * vb[1].z + pa[r].z * vb[2].z + pa[r].w * vb[3].z;
                acc[r][3] += pa[r].x * vb[0].w + pa[r].y * vb[1].w + pa[r].z * vb[2].w + pa[r].w * vb[3].w;
            }
        }
        // column sums of this tile
        {
            int jl = t & 63, ig = t >> 6;
            float cs = 0.f;
#pragma unroll
            for (int u = 0; u < 16; ++u) {
                int i = ig * 16 + u;
                cs += P[i * 64 + swz(i, jl)];
            }
            csum[ig][jl] = cs;
        }
        __syncthreads();
        if (t < 64) {
            float tot = csum[0][t] + csum[1][t] + csum[2][t] + csum[3][t];
            atomicAdd(&colsum[(size_t)(b * NH + h) * NL + (jt << 6) + t], tot);
        }
        __syncthreads();
    }
    // write Vcat
#pragma unroll
    for (int r = 0; r < 4; ++r) {
        float4 o;
        o.x = acc[r][0]; o.y = acc[r][1]; o.z = acc[r][2]; o.w = acc[r][3];
        int i = i0 + ty * 4 + r;
        *(float4*)(Vcat + ((size_t)(b << 9) + i) * ND + h * 64 + (tx << 2)) = o;
    }
}

// ---------------- token-weight softmax w[b,l] ----------------
__global__ __launch_bounds__(512) void wk_kernel(
    const int* __restrict__ tids, const float* __restrict__ colsum, float* __restrict__ wvec) {
    __shared__ float red[8];
    __shared__ int redi[8];
    int b = blockIdx.x, l = threadIdx.x;
    int lane = l & 63, wv = l >> 6;
    int padv = (tids[(b << 9) + l] != 0) ? 1 : 0;
    int cnt = padv;
    for (int off = 1; off < 64; off <<= 1) cnt += __shfl_xor(cnt, off);
    if (lane == 0) redi[wv] = cnt;
    __syncthreads();
    int ds = 0;
    for (int k = 0; k < 8; ++k) ds += redi[k];
    if (ds < 1) ds = 1;
    float cs = 0.f;
    for (int hh = 0; hh < NH; ++hh) cs += colsum[(size_t)(b * NH + hh) * NL + l];
    float x = padv ? cs / (6.f * (float)ds) : -INFINITY;
    float m = x;
    for (int off = 1; off < 64; off <<= 1) m = fmaxf(m, __shfl_xor(m, off));
    if (lane == 0) red[wv] = m;
    __syncthreads();
    float bm = red[0];
    for (int k = 1; k < 8; ++k) bm = fmaxf(bm, red[k]);
    float e = padv ? __expf(x - bm) : 0.f;
    float se = e;
    for (int off = 1; off < 64; off <<= 1) se += __shfl_xor(se, off);
    __syncthreads();
    if (lane == 0) red[wv] = se;
    __syncthreads();
    float total = 0.f;
    for (int k = 0; k < 8; ++k) total += red[k];
    wvec[(b << 9) + l] = (total > 0.f) ? e / total : 0.f;
}

// ---------------- fc + per-token softmax + weighted sum ----------------
__global__ __launch_bounds__(256) void logits_kernel(
    const float* __restrict__ Vcat, const float* __restrict__ fcw, const float* __restrict__ fcb,
    const float* __restrict__ wvec, float* __restrict__ lacc) {
    __shared__ float fwT[ND][57];
    __shared__ float vs[4][ND];
    int t = threadIdx.x;
    int b = blockIdx.x >> 2, lt = blockIdx.x & 3;
    for (int it = 0; it < 20; ++it) {
        int e = t + (it << 8);
        if (e < (NCP * ND) / 4) {
            int fe = e << 2;
            int c = fe / ND, k = fe % ND;
            float4 v = *(const float4*)(fcw + fe);
            fwT[k][c] = v.x; fwT[k + 1][c] = v.y; fwT[k + 2][c] = v.z; fwT[k + 3][c] = v.w;
        }
    }
    __syncthreads();
    int wvi = t >> 6, lane = t & 63;
    float bias = (lane < NCP) ? fcb[lane] : 0.f;
    float lsum = 0.f;
    for (int li = 0; li < 32; ++li) {
        int l = (lt << 7) + (wvi << 5) + li;
        const float* vr = Vcat + ((size_t)(b << 9) + l) * ND;
#pragma unroll
        for (int q = 0; q < 3; ++q) {
            int idx = (q << 7) + (lane << 1);
            float2 v = *(const float2*)(vr + idx);
            vs[wvi][idx] = v.x;
            vs[wvi][idx + 1] = v.y;
        }
        float g = bias;
        for (int kc = 0; kc < ND; kc += 4) {
            float4 v = *(const float4*)&vs[wvi][kc];
            if (lane < NCP)
                g += v.x * fwT[kc][lane] + v.y * fwT[kc + 1][lane] +
                     v.z * fwT[kc + 2][lane] + v.w * fwT[kc + 3][lane];
        }
        float gm = (lane < NCP) ? g : -INFINITY;
        float m = gm;
        for (int off = 1; off < 64; off <<= 1) m = fmaxf(m, __shfl_xor(m, off));
        float e = (lane < NCP) ? __expf(g - m) : 0.f;
        float ssum = e;
        for (int off = 1; off < 64; off <<= 1) ssum += __shfl_xor(ssum, off);
        float p = e / ssum;
        lsum += p * wvec[(b << 9) + l];
    }
    if (lane < NCP) atomicAdd(&lacc[b * NCP + lane], lsum);
}

// ---------------- final softmax over first 50 ----------------
__global__ __launch_bounds__(64) void final_kernel(const float* __restrict__ lacc, float* __restrict__ out) {
    int b = blockIdx.x, lane = threadIdx.x;
    float x = (lane < NC) ? lacc[b * NCP + lane] : -INFINITY;
    float m = x;
    for (int off = 1; off < 64; off <<= 1) m = fmaxf(m, __shfl_xor(m, off));
    float e = (lane < NC) ? __expf(x - m) : 0.f;
    float s = e;
    for (int off = 1; off < 64; off <<= 1) s += __shfl_xor(s, off);
    if (lane < NC) out[b * NC + lane] = e / s;
}

extern "C" void kernel_launch(void* const* d_in, const int* in_sizes, int n_in,
                              void* d_out, int out_size, void* d_ws, size_t ws_size,
                              hipStream_t stream) {
    const int* tids = (const int*)d_in[0];
    const int* TFs = (const int*)d_in[1];
    const int* DFs = (const int*)d_in[2];
    const float* emb = (const float*)d_in[3];
    const float* gamma = (const float*)d_in[4];
    const float* beta = (const float*)d_in[5];
    const float* fcw = (const float*)d_in[6];
    const float* fcb = (const float*)d_in[7];
    float* out = (float*)d_out;

    char* ws = (char*)d_ws;
    float* hw = (float*)ws;                              // 25,165,824 B
    float* q2 = (float*)(ws + 25165824);                 //    393,216 B
    float* co = (float*)(ws + 25559040);                 // 33,554,432 B (per-head reuse)
    float* Vcat = (float*)(ws + 59113472);               // 25,165,824 B
    float* rowm = (float*)(ws + 84279296);               //     65,536 B
    float* rowsum = (float*)(ws + 84344832);             //     65,536 B
    float* wvec = (float*)(ws + 84410368);               //     65,536 B
    char* zbase = ws + 84475904;                         //    400,000 B zero region
    double* stats = (double*)zbase;                      // 12 doubles (pad 128)
    float* colsum = (float*)(zbase + 128);               //    393,216 B
    float* lacc = (float*)(zbase + 128 + 393216);        //      6,656 B
    float* bnab = (float*)(ws + 84875904);               //          8 B

    zero_kernel<<<64, 256, 0, stream>>>((float4*)zbase);
    embed_kernel<<<NB * NL, ND, 0, stream>>>(tids, TFs, DFs, emb, hw, q2);
    for (int h = 0; h < NH; ++h) {
        dist_kernel<<<NB * 8, 256, 0, stream>>>(hw, q2, co, stats, h);
        fin_kernel<<<1, 64, 0, stream>>>(stats, gamma, beta, bnab, h);
        rowstats_kernel<<<NB * NL / 4, 256, 0, stream>>>(co, tids, bnab, rowm, rowsum);
        pv_kernel<<<NB * 8, 256, 0, stream>>>(co, hw, tids, bnab, rowm, rowsum, Vcat, colsum, h);
    }
    wk_kernel<<<NB, 512, 0, stream>>>(tids, colsum, wvec);
    logits_kernel<<<NB * 4, 256, 0, stream>>>(Vcat, fcw, fcb, wvec, lacc);
    final_kernel<<<NB, 64, 0, stream>>>(lacc, out);
}

// Round 2
// 1138.000 us; speedup vs baseline: 1.1789x; 1.1789x over previous
//
#include <hip/hip_runtime.h>
#include <math.h>

#define NB 32
#define NL 512
#define ND 384
#define NH 6
#define NCP 52
#define NC 50

// XOR swizzle for [row][64] f32 LDS tiles: permutes 16B chunks, keeps 4-chunks contiguous.
__device__ __forceinline__ int swz(int row, int k) {
    return k ^ (((row >> 2) & 7) << 2);
}

// ---------------- zero accumulators ----------------
__global__ void zero_kernel(float4* zb) {
    int idx = blockIdx.x * 256 + threadIdx.x;
    float4 z; z.x = 0.f; z.y = 0.f; z.z = 0.f; z.w = 0.f;
    for (int i = idx; i < 25000; i += 64 * 256) zb[i] = z;
}

// ---------------- embedding + tfidf weight + q2 ----------------
__global__ __launch_bounds__(384) void embed_kernel(
    const int* __restrict__ tids, const int* __restrict__ TFs, const int* __restrict__ DFs,
    const float* __restrict__ emb, float* __restrict__ hw, float* __restrict__ q2) {
    int t = threadIdx.x;
    int bl = blockIdx.x;               // 0..B*L-1
    int b = bl >> 9, l = bl & 511;
    int tid = tids[bl];
    float tf = log1pf(fminf((float)TFs[bl], 20.f));
    float idf = 1.f / logf((float)DFs[bl] + 2.f);
    float wt = tf * idf;
    float hv = emb[(size_t)tid * ND + t] * wt;
    int hh = t >> 6, dd = t & 63;
    hw[((size_t)(b * NH + hh) * NL + l) * 64 + dd] = hv;
    float q = hv * hv;
    for (int off = 1; off < 64; off <<= 1) q += __shfl_xor(q, off);
    if (dd == 0) q2[(b * NH + hh) * NL + l] = q;
}

// ---------------- pairwise distance + BN stats (per head) ----------------
__global__ __launch_bounds__(256) void dist_kernel(
    const float* __restrict__ hw, const float* __restrict__ q2g,
    float* __restrict__ co, double* __restrict__ stats, int h) {
    __shared__ float hjs[512 * 64];
    __shared__ float his[64 * 64];
    __shared__ float q2j[512];
    __shared__ float q2i[64];
    __shared__ float red[8];
    int t = threadIdx.x;
    int b = blockIdx.x >> 3;
    int i0 = (blockIdx.x & 7) << 6;
    const float* hb = hw + (size_t)(b * NH + h) * (NL * 64);
    for (int it = 0; it < 32; ++it) {
        int f4i = t + (it << 8);
        int row = f4i >> 4;
        int kc = (f4i & 15) << 2;
        float4 v = *(const float4*)(hb + row * 64 + kc);
        *(float4*)(hjs + row * 64 + swz(row, kc)) = v;
    }
    for (int it = 0; it < 4; ++it) {
        int f4i = t + (it << 8);
        int row = f4i >> 4;
        int kc = (f4i & 15) << 2;
        float4 v = *(const float4*)(hb + (i0 + row) * 64 + kc);
        *(float4*)(his + row * 64 + swz(row, kc)) = v;
    }
    const float* q2b = q2g + (b * NH + h) * NL;
    q2j[t] = q2b[t];
    q2j[t + 256] = q2b[t + 256];
    if (t < 64) q2i[t] = q2b[i0 + t];
    __syncthreads();

    int tx = t & 15, ty = t >> 4;
    float lsum = 0.f, lss = 0.f;
    for (int jj = 0; jj < 8; ++jj) {
        int jb = (jj << 6) + (tx << 2);
        float acc[4][4] = {};
        for (int kc = 0; kc < 64; kc += 4) {
            float4 a[4], bb[4];
#pragma unroll
            for (int r = 0; r < 4; ++r)
                a[r] = *(const float4*)(his + (ty * 4 + r) * 64 + swz(ty * 4 + r, kc));
#pragma unroll
            for (int c = 0; c < 4; ++c)
                bb[c] = *(const float4*)(hjs + (jb + c) * 64 + swz(jb + c, kc));
#pragma unroll
            for (int r = 0; r < 4; ++r)
#pragma unroll
                for (int c = 0; c < 4; ++c)
                    acc[r][c] += a[r].x * bb[c].x + a[r].y * bb[c].y + a[r].z * bb[c].z + a[r].w * bb[c].w;
        }
#pragma unroll
        for (int r = 0; r < 4; ++r) {
            int i = ty * 4 + r;
            float4 o;
            float q2iv = q2i[i];
            float d0 = q2iv + q2j[jb + 0] - 2.f * acc[r][0];
            float d1 = q2iv + q2j[jb + 1] - 2.f * acc[r][1];
            float d2 = q2iv + q2j[jb + 2] - 2.f * acc[r][2];
            float d3 = q2iv + q2j[jb + 3] - 2.f * acc[r][3];
            o.x = sqrtf(fmaxf(d0, 0.f) + 1e-12f);
            o.y = sqrtf(fmaxf(d1, 0.f) + 1e-12f);
            o.z = sqrtf(fmaxf(d2, 0.f) + 1e-12f);
            o.w = sqrtf(fmaxf(d3, 0.f) + 1e-12f);
            lsum += o.x + o.y + o.z + o.w;
            lss += o.x * o.x + o.y * o.y + o.z * o.z + o.w * o.w;
            *(float4*)(co + ((size_t)b * NL + i0 + i) * NL + jb) = o;
        }
    }
    for (int off = 1; off < 64; off <<= 1) {
        lsum += __shfl_xor(lsum, off);
        lss += __shfl_xor(lss, off);
    }
    if ((t & 63) == 0) { red[(t >> 6) * 2] = lsum; red[(t >> 6) * 2 + 1] = lss; }
    __syncthreads();
    if (t == 0) {
        float s = 0.f, ss = 0.f;
        for (int w = 0; w < 4; ++w) { s += red[w * 2]; ss += red[w * 2 + 1]; }
        atomicAdd(&stats[h * 2], (double)s);
        atomicAdd(&stats[h * 2 + 1], (double)ss);
    }
}

// ---------------- finalize BN affine for head h ----------------
__global__ void fin_kernel(const double* __restrict__ stats, const float* __restrict__ gamma,
                           const float* __restrict__ beta, float* __restrict__ bnab, int h) {
    if (threadIdx.x == 0) {
        double n = (double)NB * NL * NL;
        double mu = stats[h * 2] / n;
        double var = stats[h * 2 + 1] / n - mu * mu;
        double inv = 1.0 / sqrt(var + 1e-5);
        double a = (double)gamma[h] * inv;
        bnab[0] = (float)a;
        bnab[1] = (float)((double)beta[h] - mu * a);
    }
}

// ---------------- per-row softmax stats (per head) ----------------
__global__ __launch_bounds__(256) void rowstats_kernel(
    const float* __restrict__ co, const int* __restrict__ tids, const float* __restrict__ bnab,
    float* __restrict__ rowm, float* __restrict__ rowsum) {
    int wv = threadIdx.x >> 6, lane = threadIdx.x & 63;
    int r = blockIdx.x * 4 + wv;       // global row 0..B*L-1
    int b = r >> 9, i = r & 511;
    float a = bnab[0], bb = bnab[1];
    bool padi = tids[(b << 9) + i] != 0;
    const float* row = co + (size_t)r * NL;
    float s[8];
#pragma unroll
    for (int u2 = 0; u2 < 2; ++u2) {
        int j0 = (u2 << 8) + (lane << 2);
        float4 v = *(const float4*)(row + j0);
        int4 tj = *(const int4*)(tids + (b << 9) + j0);
        s[u2 * 4 + 0] = (padi && tj.x != 0) ? a * v.x + bb : 0.f;
        s[u2 * 4 + 1] = (padi && tj.y != 0) ? a * v.y + bb : 0.f;
        s[u2 * 4 + 2] = (padi && tj.z != 0) ? a * v.z + bb : 0.f;
        s[u2 * 4 + 3] = (padi && tj.w != 0) ? a * v.w + bb : 0.f;
    }
    float m = s[0];
#pragma unroll
    for (int u = 1; u < 8; ++u) m = fmaxf(m, s[u]);
    for (int off = 1; off < 64; off <<= 1) m = fmaxf(m, __shfl_xor(m, off));
    float sum = 0.f;
#pragma unroll
    for (int u = 0; u < 8; ++u) sum += __expf(s[u] - m);
    for (int off = 1; off < 64; off <<= 1) sum += __shfl_xor(sum, off);
    if (lane == 0) { rowm[r] = m; rowsum[r] = sum; }
}

// ---------------- softmax + PV + column sums (per head) ----------------
__global__ __launch_bounds__(256) void pv_kernel(
    const float* __restrict__ co, const float* __restrict__ hw, const int* __restrict__ tids,
    const float* __restrict__ bnab, const float* __restrict__ rowm, const float* __restrict__ rowsum,
    float* __restrict__ Vcat, float* __restrict__ colsum, int h) {
    __shared__ float P[64 * 64];
    __shared__ float Vt[64 * 64];
    __shared__ float mi[64], isi[64];
    __shared__ int padi[64];
    __shared__ float csum[4][64];
    int t = threadIdx.x;
    int b = blockIdx.x >> 3;
    int i0 = (blockIdx.x & 7) << 6;
    float a = bnab[0], bb = bnab[1];
    if (t < 64) {
        int r = (b << 9) + i0 + t;
        mi[t] = rowm[r];
        isi[t] = 1.f / rowsum[r];
        padi[t] = tids[r] != 0;
    }
    __syncthreads();
    int tx = t & 15, ty = t >> 4;
    float acc[4][4] = {};
    for (int jt = 0; jt < 8; ++jt) {
        // stage P (softmax probabilities)
        {
            int sr = t >> 2, q = t & 3;
            bool pi = padi[sr] != 0;
            float mm = mi[sr], ii = isi[sr];
#pragma unroll
            for (int u = 0; u < 4; ++u) {
                int col = (q << 4) + (u << 2);
                int j = (jt << 6) + col;
                float4 v = *(const float4*)(co + ((size_t)(b << 9) + i0 + sr) * NL + j);
                int4 tj = *(const int4*)(tids + (b << 9) + j);
                float4 p;
                p.x = __expf(((pi && tj.x != 0) ? a * v.x + bb : 0.f) - mm) * ii;
                p.y = __expf(((pi && tj.y != 0) ? a * v.y + bb : 0.f) - mm) * ii;
                p.z = __expf(((pi && tj.z != 0) ? a * v.z + bb : 0.f) - mm) * ii;
                p.w = __expf(((pi && tj.w != 0) ? a * v.w + bb : 0.f) - mm) * ii;
                *(float4*)(P + sr * 64 + swz(sr, col)) = p;
            }
        }
        // stage V tile
        {
            const float* hb = hw + (size_t)(b * NH + h) * (NL * 64) + (size_t)(jt << 6) * 64;
#pragma unroll
            for (int it = 0; it < 4; ++it) {
                int f4i = t + (it << 8);
                int row = f4i >> 4, kc = (f4i & 15) << 2;
                float4 v = *(const float4*)(hb + row * 64 + kc);
                *(float4*)(Vt + row * 64 + swz(row, kc)) = v;
            }
        }
        __syncthreads();
        // PV accumulate
        for (int jc = 0; jc < 64; jc += 4) {
            float4 pa[4], vb[4];
#pragma unroll
            for (int r = 0; r < 4; ++r)
                pa[r] = *(const float4*)(P + (ty * 4 + r) * 64 + swz(ty * 4 + r, jc));
#pragma unroll
            for (int u = 0; u < 4; ++u)
                vb[u] = *(const float4*)(Vt + (jc + u) * 64 + swz(jc + u, tx << 2));
#pragma unroll
            for (int r = 0; r < 4; ++r) {
                acc[r][0] += pa[r].x * vb[0].x + pa[r].y * vb[1].x + pa[r].z * vb[2].x + pa[r].w * vb[3].x;
                acc[r][1] += pa[r].x * vb[0].y + pa[r].y * vb[1].y + pa[r].z * vb[2].y + pa[r].w * vb[3].y;
                acc[r][2] += pa[r].x * vb[0].z + pa[r].y * vb[1].z + pa[r].z * vb[2].z + pa[r].w * vb[3].z;
                acc[r][3] += pa[r].x * vb[0].w + pa[r].y * vb[1].w + pa[r].z * vb[2].w + pa[r].w * vb[3].w;
            }
        }
        // column sums of this tile
        {
            int jl = t & 63, ig = t >> 6;
            float cs = 0.f;
#pragma unroll
            for (int u = 0; u < 16; ++u) {
                int i = ig * 16 + u;
                cs += P[i * 64 + swz(i, jl)];
            }
            csum[ig][jl] = cs;
        }
        __syncthreads();
        if (t < 64) {
            float tot = csum[0][t] + csum[1][t] + csum[2][t] + csum[3][t];
            atomicAdd(&colsum[(size_t)(b * NH + h) * NL + (jt << 6) + t], tot);
        }
        __syncthreads();
    }
    // write Vcat
#pragma unroll
    for (int r = 0; r < 4; ++r) {
        float4 o;
        o.x = acc[r][0]; o.y = acc[r][1]; o.z = acc[r][2]; o.w = acc[r][3];
        int i = i0 + ty * 4 + r;
        *(float4*)(Vcat + ((size_t)(b << 9) + i) * ND + h * 64 + (tx << 2)) = o;
    }
}

// ---------------- token-weight softmax w[b,l] ----------------
__global__ __launch_bounds__(512) void wk_kernel(
    const int* __restrict__ tids, const float* __restrict__ colsum, float* __restrict__ wvec) {
    __shared__ float red[8];
    __shared__ int redi[8];
    int b = blockIdx.x, l = threadIdx.x;
    int lane = l & 63, wv = l >> 6;
    int padv = (tids[(b << 9) + l] != 0) ? 1 : 0;
    int cnt = padv;
    for (int off = 1; off < 64; off <<= 1) cnt += __shfl_xor(cnt, off);
    if (lane == 0) redi[wv] = cnt;
    __syncthreads();
    int ds = 0;
    for (int k = 0; k < 8; ++k) ds += redi[k];
    if (ds < 1) ds = 1;
    float cs = 0.f;
    for (int hh = 0; hh < NH; ++hh) cs += colsum[(size_t)(b * NH + hh) * NL + l];
    float x = padv ? cs / (6.f * (float)ds) : -INFINITY;
    float m = x;
    for (int off = 1; off < 64; off <<= 1) m = fmaxf(m, __shfl_xor(m, off));
    if (lane == 0) red[wv] = m;
    __syncthreads();
    float bm = red[0];
    for (int k = 1; k < 8; ++k) bm = fmaxf(bm, red[k]);
    float e = padv ? __expf(x - bm) : 0.f;
    float se = e;
    for (int off = 1; off < 64; off <<= 1) se += __shfl_xor(se, off);
    __syncthreads();
    if (lane == 0) red[wv] = se;
    __syncthreads();
    float total = 0.f;
    for (int k = 0; k < 8; ++k) total += red[k];
    wvec[(b << 9) + l] = (total > 0.f) ? e / total : 0.f;
}

// ---------------- fc + per-token softmax + weighted sum ----------------
// One wave = 4 tokens; lane = class. Weight read straight from L1/L2 (80 KB,
// fully cache-resident, each 64B line reused over 4 consecutive k-steps).
// Vcat rows are wave-uniform broadcast loads. LDS is 1 KB -> high occupancy.
__global__ __launch_bounds__(256) void logits_kernel(
    const float* __restrict__ Vcat, const float* __restrict__ fcw, const float* __restrict__ fcb,
    const float* __restrict__ wvec, float* __restrict__ lacc) {
    __shared__ float red[4][64];
    int t = threadIdx.x;
    int wv = t >> 6, lane = t & 63;
    int tok0 = (blockIdx.x * 4 + wv) * 4;    // 16 consecutive tokens per block
    int b = tok0 >> 9;                       // all 16 in the same batch row
    int wrow = (lane < NCP) ? lane : (NCP - 1);
    const float* wp = fcw + wrow * ND;
    const float* vp = Vcat + (size_t)tok0 * ND;
    float acc0 = 0.f, acc1 = 0.f, acc2 = 0.f, acc3 = 0.f;
#pragma unroll 2
    for (int kc = 0; kc < ND; kc += 4) {
        float4 w4 = *(const float4*)(wp + kc);
        float4 v0 = *(const float4*)(vp + kc);
        float4 v1 = *(const float4*)(vp + ND + kc);
        float4 v2 = *(const float4*)(vp + 2 * ND + kc);
        float4 v3 = *(const float4*)(vp + 3 * ND + kc);
        acc0 += v0.x * w4.x + v0.y * w4.y + v0.z * w4.z + v0.w * w4.w;
        acc1 += v1.x * w4.x + v1.y * w4.y + v1.z * w4.z + v1.w * w4.w;
        acc2 += v2.x * w4.x + v2.y * w4.y + v2.z * w4.z + v2.w * w4.w;
        acc3 += v3.x * w4.x + v3.y * w4.y + v3.z * w4.z + v3.w * w4.w;
    }
    float bias = fcb[wrow];
    float g[4] = {acc0 + bias, acc1 + bias, acc2 + bias, acc3 + bias};
    float lsum = 0.f;
#pragma unroll
    for (int u = 0; u < 4; ++u) {
        float gm = (lane < NCP) ? g[u] : -INFINITY;
        float m = gm;
        for (int off = 1; off < 64; off <<= 1) m = fmaxf(m, __shfl_xor(m, off));
        float e = (lane < NCP) ? __expf(g[u] - m) : 0.f;
        float s = e;
        for (int off = 1; off < 64; off <<= 1) s += __shfl_xor(s, off);
        lsum += (e / s) * wvec[tok0 + u];
    }
    red[wv][lane] = lsum;
    __syncthreads();
    if (wv == 0) {
        float tot = red[0][lane] + red[1][lane] + red[2][lane] + red[3][lane];
        if (lane < NCP) atomicAdd(&lacc[b * NCP + lane], tot);
    }
}

// ---------------- final softmax over first 50 ----------------
__global__ __launch_bounds__(64) void final_kernel(const float* __restrict__ lacc, float* __restrict__ out) {
    int b = blockIdx.x, lane = threadIdx.x;
    float x = (lane < NC) ? lacc[b * NCP + lane] : -INFINITY;
    float m = x;
    for (int off = 1; off < 64; off <<= 1) m = fmaxf(m, __shfl_xor(m, off));
    float e = (lane < NC) ? __expf(x - m) : 0.f;
    float s = e;
    for (int off = 1; off < 64; off <<= 1) s += __shfl_xor(s, off);
    if (lane < NC) out[b * NC + lane] = e / s;
}

extern "C" void kernel_launch(void* const* d_in, const int* in_sizes, int n_in,
                              void* d_out, int out_size, void* d_ws, size_t ws_size,
                              hipStream_t stream) {
    const int* tids = (const int*)d_in[0];
    const int* TFs = (const int*)d_in[1];
    const int* DFs = (const int*)d_in[2];
    const float* emb = (const float*)d_in[3];
    const float* gamma = (const float*)d_in[4];
    const float* beta = (const float*)d_in[5];
    const float* fcw = (const float*)d_in[6];
    const float* fcb = (const float*)d_in[7];
    float* out = (float*)d_out;

    char* ws = (char*)d_ws;
    float* hw = (float*)ws;                              // 25,165,824 B
    float* q2 = (float*)(ws + 25165824);                 //    393,216 B
    float* co = (float*)(ws + 25559040);                 // 33,554,432 B (per-head reuse)
    float* Vcat = (float*)(ws + 59113472);               // 25,165,824 B
    float* rowm = (float*)(ws + 84279296);               //     65,536 B
    float* rowsum = (float*)(ws + 84344832);             //     65,536 B
    float* wvec = (float*)(ws + 84410368);               //     65,536 B
    char* zbase = ws + 84475904;                         //    400,000 B zero region
    double* stats = (double*)zbase;                      // 12 doubles (pad 128)
    float* colsum = (float*)(zbase + 128);               //    393,216 B
    float* lacc = (float*)(zbase + 128 + 393216);        //      6,656 B
    float* bnab = (float*)(ws + 84875904);               //          8 B

    zero_kernel<<<64, 256, 0, stream>>>((float4*)zbase);
    embed_kernel<<<NB * NL, ND, 0, stream>>>(tids, TFs, DFs, emb, hw, q2);
    for (int h = 0; h < NH; ++h) {
        dist_kernel<<<NB * 8, 256, 0, stream>>>(hw, q2, co, stats, h);
        fin_kernel<<<1, 64, 0, stream>>>(stats, gamma, beta, bnab, h);
        rowstats_kernel<<<NB * NL / 4, 256, 0, stream>>>(co, tids, bnab, rowm, rowsum);
        pv_kernel<<<NB * 8, 256, 0, stream>>>(co, hw, tids, bnab, rowm, rowsum, Vcat, colsum, h);
    }
    wk_kernel<<<NB, 512, 0, stream>>>(tids, colsum, wvec);
    logits_kernel<<<NB * 4, 256, 0, stream>>>(Vcat, fcw, fcb, wvec, lacc);
    final_kernel<<<NB, 64, 0, stream>>>(lacc, out);
}